// Round 7
// baseline (158.349 us; speedup 1.0000x reference)
//
#include <hip/hip_runtime.h>
#include <hip/hip_bf16.h>
#include <math.h>

// ---- static config ----
#define B_     8
#define CIN_   32
#define COUT_  32
#define H_     256
#define W_     256
#define K_     36
#define P_     3
#define KW_    7
#define TAPS_  49
#define NPAIR_ 25    // 24 full pairs + 1 singleton (tap 48 + zero pad)
#define EPS_   1e-5f
#define SLOPE_ 0.2f

// ws layout:
//   bytes [0 .. 102400)          kerB bf16 frags [4 oct][25 pair][64 lane][8]
//   bytes [102400 .. +512K)      partials float2 [256 bo][256 tile]
//   bytes [626688 .. +2K)        meanrs float2 [256 bo]
#define PART_OFF_F   25600   // float offset of partials
#define MEANRS_OFF_F 156672  // float offset of meanrs

// Img_s: fp32, 2 planes [ci-quad][20 py][21 px][4 ci], plane 6736 B
#define IMG_PLANE_B   6736
#define IMG_ROW_B     336

// Xup: ONE ci-octet per pass, parity-split. r15 strides chosen so the
// four 16-lane groups of a stage-3 ds_read_b128 land on distinct bank
// phases mod 128 B:  2*XP_ROW = 672 == 32 (mod 128), XO_BASE == 64.
//   even-x: 37 rows x 19 entries used (21-entry stride) base 0,    12432 B
//   odd-x:  37 rows x 19 entries (x=1..35, pad@18)     base 12480, 12432 B
// entry = 16 B (8 bf16 ci octet). row stride 336 B. total 24912 B.
#define XP_ROW   336
#define XO_BASE  12480

using short8_t  = __attribute__((ext_vector_type(8)))  short;
using f32x16_t  = __attribute__((ext_vector_type(16))) float;
using f32x4_t   = __attribute__((ext_vector_type(4)))  float;

__device__ inline ushort f32_to_bf16(float f) {
    unsigned int bits = __float_as_uint(f);
    unsigned int r = (bits + 0x7FFFu + ((bits >> 16) & 1u)) >> 16;
    return (ushort)r;
}

// ============================================================
// Kernel A: build B-fragments, row-major tap-pair packing.
// grid = 100 (= 4 oct x 25 pair). Pair i covers taps (2i, 2i+1) of the
// linearized 7x7 stencil; tap 49 (i=24, gs=1) is zero.
// Frag lane (n=lane&31, gs=lane>>5), j=0..7:
//   value = dense_kernel[n][oct*8+j][tap 2i+gs], 0 if tap > 48.
// ============================================================
__global__ __launch_bounds__(256)
void build_kernel(const float* __restrict__ weight, ushort* __restrict__ kerB) {
    __shared__ float psi_s[2][K_];            // psi for taps 2i, 2i+1
    const int f  = blockIdx.x;
    const int i  = f % NPAIR_;
    const int oc = f / NPAIR_;
    const int tid = threadIdx.x;

    if (tid < 2 * K_) {
        const int tt = tid / K_;              // which tap of the pair
        const int k  = tid - tt * K_;
        const int tap = 2 * i + tt;
        float val = 0.f;
        if (tap <= 48) {
            const int ky = tap / 7;
            const int kx = tap % 7;
            const double dxy   = 2.0 / 512.0;
            const double rcut  = 0.015;       // RADIUS_CUTOFF / 2
            const int    nr    = 6, nphi = 7;
            const double dr    = rcut / nr;
            const double dphi  = 2.0 * M_PI / nphi;
            const double norm  = M_PI * (rcut * nr / (nr + 1)) * (rcut * nr / (nr + 1));
            const double q     = dxy * dxy;
            const double offy = (double)(ky - P_) * dxy;
            const double offx = (double)(kx - P_) * dxy;
            const double r    = sqrt(offx * offx + offy * offy);
            double phi = atan2(offy, offx);
            if (phi < 0.0) phi += 2.0 * M_PI;
            double ir, iphi;
            if (k == 0) { ir = 0.0; iphi = 0.0; }
            else        { ir = (double)((k - 1) / nphi + 1) * dr;
                          iphi = (double)((k - 1) % nphi) * dphi; }
            double rv = 1.0 - fabs(r - ir) / dr;
            rv = rv > 0.0 ? rv : 0.0;
            if (r > rcut) rv = 0.0;
            double pv = 1.0;
            if (k > 0) {
                double da = fabs(phi - iphi);
                double dm = da < (2.0 * M_PI - da) ? da : (2.0 * M_PI - da);
                pv = 1.0 - dm / dphi;
                pv = pv > 0.0 ? pv : 0.0;
            }
            val = (float)(rv * pv * q / norm);
        }
        psi_s[tt][k] = val;
    }
    __syncthreads();

    for (int e = tid; e < 512; e += 256) {
        const int lane = e >> 3;
        const int j    = e & 7;
        const int gs   = lane >> 5;
        const int n    = lane & 31;
        const int tap  = 2 * i + gs;
        float s = 0.f;
        if (tap <= 48) {
            const int ci = oc * 8 + j;
            const float* w = weight + (size_t)(n * CIN_ + ci) * K_;
            #pragma unroll
            for (int k = 0; k < K_; ++k) s = fmaf(w[k], psi_s[gs][k], s);
        }
        kerB[((size_t)f * 64 + lane) * 8 + j] = f32_to_bf16(s);
    }
}

// ============================================================
// Kernel B: fused upsample + implicit-GEMM conv + stats partials.
// grid = (16,16,B), block = 512 (8 waves). Tile = 16x16 pixels x 32 cout.
// r15: (1) row-major tap pairing -> 25 MFMAs/pass (was 28), -11% MFMA
//   and -11% a-frag LDS reads; pair halves straddling rows compute
//   per-half addresses from compile-time constants.
// (2) XP_ROW=336 / XO_BASE=12480 -> the four 16-lane groups of each
//   stage-3 ds_read_b128 sit on distinct bank phases (mod 128 B).
// ============================================================
__global__ __launch_bounds__(512, 8)
void conv_mfma(const float* __restrict__ image,
               const ushort* __restrict__ kerB,
               float* __restrict__ out,
               float* __restrict__ partials) {
    __shared__ float  Img_s[3368];            // 13472 B (2 planes x 6736 B)
    __shared__ ushort Xup_s[12456];           // 24912 B (parity-split, 1 octet)
    __shared__ float  wp[8][32][2];           // per-wave stats partials

    const int tid  = threadIdx.x;
    const int lane = tid & 63;
    const int w    = tid >> 6;                // wave 0..7 = M-tile index
    const int j0 = blockIdx.x * 16;
    const int i0 = blockIdx.y * 16;
    const int b  = blockIdx.z;

    const int u0 = 2 * i0 - 3;
    const int v0 = 2 * j0 - 3;
    const int R0 = i0 - 2;                    // unclamped patch origin (rows)
    const int C0 = j0 - 2;                    // unclamped patch origin (cols)

    // A-fragment lane mapping (32x32x16): m = lane&31, k-half gs = lane>>5
    const int gs  = lane >> 5;                // which tap of the pair
    const int tio = (lane & 31) >> 4;
    const int tj  = lane & 15;
    const int yb0 = 4 * w + 2 * tio;

    f32x16_t acc;
    #pragma unroll
    for (int q = 0; q < 16; ++q) acc[q] = 0.f;

    char* img_bytes = (char*)Img_s;
    char* xup_bytes = (char*)Xup_s;

    const float* imgb = image + (size_t)(b * CIN_) * (H_ * W_);

    for (int oc = 0; oc < 4; ++oc) {
        // ---- stage 1: 20x20 patch, 2 ci-quad planes of this octet ----
        const float* img = imgb + (size_t)(oc * 8) * (H_ * W_);
        for (int e = tid; e < 800; e += 512) {
            const int p  = (e >= 400) ? 1 : 0;       // ci quad within octet
            const int yx = e - p * 400;
            const int py = yx / 20, px = yx - py * 20;
            const int row = R0 + py, col = C0 + px;
            f32x4_t g = {0.f, 0.f, 0.f, 0.f};
            if ((unsigned)row < 256u && (unsigned)col < 256u) {
                const float* q = img + (size_t)p * 4 * (H_ * W_) + row * W_ + col;
                g[0] = q[0];
                g[1] = q[H_ * W_];
                g[2] = q[2 * (H_ * W_)];
                g[3] = q[3 * (H_ * W_)];
            }
            *(f32x4_t*)(img_bytes + p * IMG_PLANE_B + (py * 21 + px) * 16) = g;
        }
        __syncthreads();

        // ---- stage 2: closed-form polyphase upsample, x-pair per item ----
        // ry = y>>1, wy = ((y&1)?510:255 - (R0+ry))/511 (align_corners 2x).
        for (int e = tid; e < 703; e += 512) {
            const int y   = e / 19;
            const int xp  = e - 19 * y;
            const int x   = 2 * xp;
            const int ry  = y >> 1;
            const float wy =
                (float)((((y & 1) ? 510 : 255)) - (R0 + ry)) * (1.0f / 511.0f);
            const int Ax = C0 + xp;
            const float wx0 = (float)(255 - Ax) * (1.0f / 511.0f);
            const float wx1 = (float)(510 - Ax) * (1.0f / 511.0f);
            const bool oky = ((unsigned)(u0 + y) < 512u);
            const bool ok0 = oky && ((unsigned)(v0 + x) < 512u);
            const bool ok1 = oky && ((unsigned)(v0 + x + 1) < 512u) && (xp < 18);

            const char* lo = img_bytes + (ry * 21 + xp) * 16;
            const char* hi = lo + IMG_PLANE_B;
            const f32x4_t a00 = *(const f32x4_t*)(lo);
            const f32x4_t a01 = *(const f32x4_t*)(lo + 16);
            const f32x4_t a10 = *(const f32x4_t*)(lo + IMG_ROW_B);
            const f32x4_t a11 = *(const f32x4_t*)(lo + IMG_ROW_B + 16);
            const f32x4_t b00 = *(const f32x4_t*)(hi);
            const f32x4_t b01 = *(const f32x4_t*)(hi + 16);
            const f32x4_t b10 = *(const f32x4_t*)(hi + IMG_ROW_B);
            const f32x4_t b11 = *(const f32x4_t*)(hi + IMG_ROW_B + 16);

            const f32x4_t cA0 = a00 + wy * (a10 - a00);
            const f32x4_t cA1 = a01 + wy * (a11 - a01);
            const f32x4_t cB0 = b00 + wy * (b10 - b00);
            const f32x4_t cB1 = b01 + wy * (b11 - b01);

            // even output -> even buffer (linear store)
            {
                const f32x4_t va = cA0 + wx0 * (cA1 - cA0);
                const f32x4_t vb = cB0 + wx0 * (cB1 - cB0);
                __hip_bfloat162 h0 = __float22bfloat162_rn(make_float2(va[0], va[1]));
                __hip_bfloat162 h1 = __float22bfloat162_rn(make_float2(va[2], va[3]));
                __hip_bfloat162 h2 = __float22bfloat162_rn(make_float2(vb[0], vb[1]));
                __hip_bfloat162 h3 = __float22bfloat162_rn(make_float2(vb[2], vb[3]));
                union { short8_t s8; uint4 u4; } pk;
                pk.u4.x = ok0 ? *(unsigned int*)&h0 : 0u;
                pk.u4.y = ok0 ? *(unsigned int*)&h1 : 0u;
                pk.u4.z = ok0 ? *(unsigned int*)&h2 : 0u;
                pk.u4.w = ok0 ? *(unsigned int*)&h3 : 0u;
                *(short8_t*)(xup_bytes + y * XP_ROW + xp * 16) = pk.s8;
            }
            // odd output -> odd buffer; xp==18 writes the zero pad entry
            // (pad stays 0 for every row -- the i=24/gs=1 singleton reads it)
            {
                const f32x4_t va = cA0 + wx1 * (cA1 - cA0);
                const f32x4_t vb = cB0 + wx1 * (cB1 - cB0);
                __hip_bfloat162 h0 = __float22bfloat162_rn(make_float2(va[0], va[1]));
                __hip_bfloat162 h1 = __float22bfloat162_rn(make_float2(va[2], va[3]));
                __hip_bfloat162 h2 = __float22bfloat162_rn(make_float2(vb[0], vb[1]));
                __hip_bfloat162 h3 = __float22bfloat162_rn(make_float2(vb[2], vb[3]));
                union { short8_t s8; uint4 u4; } pk;
                pk.u4.x = ok1 ? *(unsigned int*)&h0 : 0u;
                pk.u4.y = ok1 ? *(unsigned int*)&h1 : 0u;
                pk.u4.z = ok1 ? *(unsigned int*)&h2 : 0u;
                pk.u4.w = ok1 ? *(unsigned int*)&h3 : 0u;
                *(short8_t*)(xup_bytes + XO_BASE + y * XP_ROW + xp * 16) = pk.s8;
            }
        }
        __syncthreads();

        // ---- stage 3: 25 pair-MFMAs; per-half (gs) tap address from
        //      compile-time constants. Tap t -> row yb0 + t/7, parity
        //      buffer (t%7)&1, entry tj + (t%7)>>1.
        const int abase = yb0 * XP_ROW + tj * 16;
        const ushort* kbp = kerB + ((size_t)(oc * NPAIR_) * 64 + lane) * 8;
        short8_t bf[5];
        #pragma unroll
        for (int gq = 0; gq < 5; ++gq) {
            #pragma unroll
            for (int u = 0; u < 5; ++u)
                bf[u] = *(const short8_t*)(kbp + (size_t)((gq * 5 + u) * 512));
            #pragma unroll
            for (int u = 0; u < 5; ++u) {
                const int i = gq * 5 + u;
                int addr;
                if (i < 24) {
                    const int t0 = 2 * i, t1 = 2 * i + 1;
                    const int c0 = (t0 / 7) * XP_ROW + ((t0 % 7) & 1 ? XO_BASE : 0)
                                 + ((t0 % 7) >> 1) * 16;
                    const int c1 = (t1 / 7) * XP_ROW + ((t1 % 7) & 1 ? XO_BASE : 0)
                                 + ((t1 % 7) >> 1) * 16;
                    addr = abase + (gs ? c1 : c0);
                } else {
                    // singleton: gs=0 -> tap 48 (row +6, even entry tj+3);
                    // gs=1 -> always-zero odd pad entry (broadcast)
                    const int c0 = 6 * XP_ROW + 3 * 16;
                    addr = gs ? (XO_BASE + yb0 * XP_ROW + 18 * 16)
                              : (abase + c0);
                }
                const short8_t afrag = *(const short8_t*)(xup_bytes + addr);
                acc = __builtin_amdgcn_mfma_f32_32x32x16_bf16(afrag, bf[u], acc, 0, 0, 0);
            }
        }
        __syncthreads();   // before next pass's staging overwrites LDS
    }

    // ---- epilogue: C-writes (layout col n=lane&31, row m=(q&3)+8*(q>>2)+4*gs)
    const int n = lane & 31;
    float* op = out + (size_t)(b * COUT_ + n) * (H_ * W_);
    const int ibase = i0 + 2 * w;
    #pragma unroll
    for (int grp = 0; grp < 4; ++grp) {
        const int ti  = ibase + (grp >> 1);
        const int tjj = j0 + ((grp & 1) ? 8 : 0) + 4 * gs;
        f32x4_t s;
        s[0] = acc[grp * 4 + 0]; s[1] = acc[grp * 4 + 1];
        s[2] = acc[grp * 4 + 2]; s[3] = acc[grp * 4 + 3];
        *(f32x4_t*)(op + (size_t)ti * W_ + tjj) = s;
    }

    // ---- epilogue: InstanceNorm partial sums from registers ----
    float s1 = 0.f, s2 = 0.f;
    #pragma unroll
    for (int q = 0; q < 16; ++q) { s1 += acc[q]; s2 = fmaf(acc[q], acc[q], s2); }
    s1 += __shfl_xor(s1, 32);
    s2 += __shfl_xor(s2, 32);
    if (lane < 32) { wp[w][lane][0] = s1; wp[w][lane][1] = s2; }
    __syncthreads();
    if (tid < 32) {
        float t1 = 0.f, t2 = 0.f;
        #pragma unroll
        for (int wv = 0; wv < 8; ++wv) { t1 += wp[wv][tid][0]; t2 += wp[wv][tid][1]; }
        const int tile = blockIdx.y * 16 + blockIdx.x;
        float2* pp = (float2*)partials;
        pp[((b * 32 + tid) << 8) | tile] = make_float2(t1, t2);
    }
}

// ============================================================
// Kernel C1: per-channel stats finalize. grid = 256 (one wave each).
// Fixed-order shfl tree -> deterministic.
// ============================================================
__global__ __launch_bounds__(64)
void stats_kernel(const float* __restrict__ partials, float* __restrict__ meanrs) {
    const int bo = blockIdx.x;                 // channel (b*32+o)
    const int l  = threadIdx.x;                // 0..63
    const float2* pp = (const float2*)partials + ((size_t)bo << 8);
    float s1 = 0.f, s2 = 0.f;
    #pragma unroll
    for (int k = 0; k < 4; ++k) {
        const float2 p = pp[l + 64 * k];
        s1 += p.x; s2 += p.y;
    }
    #pragma unroll
    for (int off = 32; off > 0; off >>= 1) {
        s1 += __shfl_down(s1, off);
        s2 += __shfl_down(s2, off);
    }
    if (l == 0) {
        const float inv = 1.0f / 65536.0f;
        const float m   = s1 * inv;
        const float var = s2 * inv - m * m;
        ((float2*)meanrs)[bo] = make_float2(m, 1.0f / sqrtf(var + EPS_));
    }
}

// ============================================================
// Kernel C2: pure-stream normalize + LeakyReLU (no LDS, no barriers).
// grid = 16384, block = 256.
// ============================================================
__global__ __launch_bounds__(256)
void norm2_kernel(float* __restrict__ y, const float* __restrict__ meanrs) {
    const int blk = blockIdx.x;
    const int bo  = blk >> 6;                  // 64 blocks per channel
    const float2 mr = ((const float2*)meanrs)[bo];
    const float m  = mr.x;
    const float rs = mr.y;

    const int e = blk * 256 + threadIdx.x;     // float4 index
    float4 v = ((const float4*)y)[e];
    v.x = (v.x - m) * rs; v.x = v.x >= 0.f ? v.x : SLOPE_ * v.x;
    v.y = (v.y - m) * rs; v.y = v.y >= 0.f ? v.y : SLOPE_ * v.y;
    v.z = (v.z - m) * rs; v.z = v.z >= 0.f ? v.z : SLOPE_ * v.z;
    v.w = (v.w - m) * rs; v.w = v.w >= 0.f ? v.w : SLOPE_ * v.w;
    ((float4*)y)[e] = v;
}

// ============================================================
extern "C" void kernel_launch(void* const* d_in, const int* in_sizes, int n_in,
                              void* d_out, int out_size, void* d_ws, size_t ws_size,
                              hipStream_t stream) {
    const float* image  = (const float*)d_in[0];
    const float* weight = (const float*)d_in[1];
    float*  out      = (float*)d_out;
    ushort* kerB     = (ushort*)d_ws;
    float*  partials = (float*)d_ws + PART_OFF_F;
    float*  meanrs   = (float*)d_ws + MEANRS_OFF_F;

    build_kernel<<<dim3(4 * NPAIR_), dim3(256), 0, stream>>>(weight, kerB);
    conv_mfma<<<dim3(16, 16, B_), dim3(512), 0, stream>>>(image, kerB, out, partials);
    stats_kernel<<<dim3(256), dim3(64), 0, stream>>>(partials, meanrs);
    norm2_kernel<<<dim3(16384), dim3(256), 0, stream>>>(out, meanrs);
}

// Round 8
// 116.804 us; speedup vs baseline: 1.3557x; 1.3557x over previous
//
#include <hip/hip_runtime.h>
#include <hip/hip_bf16.h>
#include <math.h>

// ---- static config ----
#define B_     8
#define CIN_   32
#define COUT_  32
#define H_     256
#define W_     256
#define K_     36
#define P_     3
#define KW_    7
#define TAPS_  49
#define NPAIR_ 25    // 21 within-row pairs (kx 0..5) + 4 kx=6 column pairs
#define EPS_   1e-5f
#define SLOPE_ 0.2f

// ws layout:
//   bytes [0 .. 102400)          kerB bf16 frags [4 oct][25 pair][64 lane][8]
//   bytes [102400 .. +512K)      partials float2 [256 bo][256 tile]
//   bytes [626688 .. +2K)        meanrs float2 [256 bo]
#define PART_OFF_F   25600   // float offset of partials
#define MEANRS_OFF_F 156672  // float offset of meanrs

// Img_s: fp32, 2 planes [ci-quad][20 py][21 px][4 ci], plane 6736 B
#define IMG_PLANE_B   6736
#define IMG_ROW_B     336

// Xup: ONE ci-octet per pass, parity-split, 38 rows (row 37 = zero pad
// read by the (ky6,pad) half of the last column pair):
//   even-x: 38 rows x 19 entries  base 0      11552 B
//   odd-x:  38 rows x 19 entries  base 11552  11552 B
// entry = 16 B (8 bf16 ci octet). row stride 304 B (=19*16 -> stage-2
// stores stay perfectly linear across y boundaries). total 23104 B.
#define XP_ROW   304
#define XO_BASE  11552

using short8_t  = __attribute__((ext_vector_type(8)))  short;
using f32x16_t  = __attribute__((ext_vector_type(16))) float;
using f32x4_t   = __attribute__((ext_vector_type(4)))  float;

__device__ inline ushort f32_to_bf16(float f) {
    unsigned int bits = __float_as_uint(f);
    unsigned int r = (bits + 0x7FFFu + ((bits >> 16) & 1u)) >> 16;
    return (ushort)r;
}

// pair pi, half tt -> linear tap (0..48), or -1 if zero pad
__host__ __device__ inline int pair_tap(int pi, int tt) {
    if (pi < 21) {
        const int ky = pi / 3, c = pi % 3;
        return ky * 7 + 2 * c + tt;
    }
    const int row = 2 * (pi - 21) + tt;
    return (row <= 6) ? (row * 7 + 6) : -1;
}

// ============================================================
// Kernel A: build B-fragments in the 25-pair packing.
// grid = 100 (= 4 oct x 25 pair). Frag lane (n=lane&31, gs=lane>>5),
// j=0..7: value = dense_kernel[n][oct*8+j][pair_tap(pi,gs)], 0 if pad.
// ============================================================
__global__ __launch_bounds__(256)
void build_kernel(const float* __restrict__ weight, ushort* __restrict__ kerB) {
    __shared__ float psi_s[2][K_];            // psi for the pair's two taps
    const int f  = blockIdx.x;
    const int pi = f % NPAIR_;
    const int oc = f / NPAIR_;
    const int tid = threadIdx.x;

    if (tid < 2 * K_) {
        const int tt = tid / K_;              // which tap of the pair
        const int k  = tid - tt * K_;
        const int tap = pair_tap(pi, tt);
        float val = 0.f;
        if (tap >= 0) {
            const int ky = tap / 7;
            const int kx = tap % 7;
            const double dxy   = 2.0 / 512.0;
            const double rcut  = 0.015;       // RADIUS_CUTOFF / 2
            const int    nr    = 6, nphi = 7;
            const double dr    = rcut / nr;
            const double dphi  = 2.0 * M_PI / nphi;
            const double norm  = M_PI * (rcut * nr / (nr + 1)) * (rcut * nr / (nr + 1));
            const double q     = dxy * dxy;
            const double offy = (double)(ky - P_) * dxy;
            const double offx = (double)(kx - P_) * dxy;
            const double r    = sqrt(offx * offx + offy * offy);
            double phi = atan2(offy, offx);
            if (phi < 0.0) phi += 2.0 * M_PI;
            double ir, iphi;
            if (k == 0) { ir = 0.0; iphi = 0.0; }
            else        { ir = (double)((k - 1) / nphi + 1) * dr;
                          iphi = (double)((k - 1) % nphi) * dphi; }
            double rv = 1.0 - fabs(r - ir) / dr;
            rv = rv > 0.0 ? rv : 0.0;
            if (r > rcut) rv = 0.0;
            double pv = 1.0;
            if (k > 0) {
                double da = fabs(phi - iphi);
                double dm = da < (2.0 * M_PI - da) ? da : (2.0 * M_PI - da);
                pv = 1.0 - dm / dphi;
                pv = pv > 0.0 ? pv : 0.0;
            }
            val = (float)(rv * pv * q / norm);
        }
        psi_s[tt][k] = val;
    }
    __syncthreads();

    for (int e = tid; e < 512; e += 256) {
        const int lane = e >> 3;
        const int j    = e & 7;
        const int gs   = lane >> 5;
        const int n    = lane & 31;
        float s = 0.f;
        if (pair_tap(pi, gs) >= 0) {
            const int ci = oc * 8 + j;
            const float* w = weight + (size_t)(n * CIN_ + ci) * K_;
            #pragma unroll
            for (int k = 0; k < K_; ++k) s = fmaf(w[k], psi_s[gs][k], s);
        }
        kerB[((size_t)f * 64 + lane) * 8 + j] = f32_to_bf16(s);
    }
}

// ============================================================
// Kernel B: fused upsample + implicit-GEMM conv + stats partials.
// grid = (16,16,B), block = 512 (8 waves). Tile = 16x16 pixels x 32 cout.
// r16 = r14 body + minimal-MFMA 25-pair packing with INCREMENTAL
// addressing (no per-pair gs-selects -- r15's spill trap):
//   group A (21): taps (ky,2c)+(ky,2c+1), addr = baseA + ky*304 + c*16
//   group B (4):  taps (2q,6)+(2q+1,6),  addr = baseB + q*608
// (ky6,pad) half reads pre-zeroed Xup row 37.
// ============================================================
__global__ __launch_bounds__(512, 8)
void conv_mfma(const float* __restrict__ image,
               const ushort* __restrict__ kerB,
               float* __restrict__ out,
               float* __restrict__ partials) {
    __shared__ float  Img_s[3368];            // 13472 B (2 planes x 6736 B)
    __shared__ ushort Xup_s[11552];           // 23104 B (parity-split, 38 rows)
    __shared__ float  wp[8][32][2];           // per-wave stats partials

    const int tid  = threadIdx.x;
    const int lane = tid & 63;
    const int w    = tid >> 6;                // wave 0..7 = M-tile index
    const int j0 = blockIdx.x * 16;
    const int i0 = blockIdx.y * 16;
    const int b  = blockIdx.z;

    const int u0 = 2 * i0 - 3;
    const int v0 = 2 * j0 - 3;
    const int R0 = i0 - 2;                    // unclamped patch origin (rows)
    const int C0 = j0 - 2;                    // unclamped patch origin (cols)

    // A-fragment lane mapping (32x32x16): m = lane&31, k-half gs = lane>>5
    const int gs  = lane >> 5;                // which tap of the pair
    const int tio = (lane & 31) >> 4;
    const int tj  = lane & 15;
    const int yb0 = 4 * w + 2 * tio;

    f32x16_t acc;
    #pragma unroll
    for (int q = 0; q < 16; ++q) acc[q] = 0.f;

    char* img_bytes = (char*)Img_s;
    char* xup_bytes = (char*)Xup_s;

    // zero Xup row 37 (even buffer) once; never overwritten afterwards
    if (tid < 19) {
        const short8_t z = {0,0,0,0,0,0,0,0};
        *(short8_t*)(xup_bytes + 37 * XP_ROW + tid * 16) = z;
    }

    const float* imgb = image + (size_t)(b * CIN_) * (H_ * W_);

    for (int oc = 0; oc < 4; ++oc) {
        // ---- stage 1: 20x20 patch, 2 ci-quad planes of this octet ----
        const float* img = imgb + (size_t)(oc * 8) * (H_ * W_);
        for (int e = tid; e < 800; e += 512) {
            const int p  = (e >= 400) ? 1 : 0;       // ci quad within octet
            const int yx = e - p * 400;
            const int py = yx / 20, px = yx - py * 20;
            const int row = R0 + py, col = C0 + px;
            f32x4_t g = {0.f, 0.f, 0.f, 0.f};
            if ((unsigned)row < 256u && (unsigned)col < 256u) {
                const float* q = img + (size_t)p * 4 * (H_ * W_) + row * W_ + col;
                g[0] = q[0];
                g[1] = q[H_ * W_];
                g[2] = q[2 * (H_ * W_)];
                g[3] = q[3 * (H_ * W_)];
            }
            *(f32x4_t*)(img_bytes + p * IMG_PLANE_B + (py * 21 + px) * 16) = g;
        }
        __syncthreads();

        // ---- stage 2: closed-form polyphase upsample, x-pair per item ----
        // ry = y>>1, wy = ((y&1)?510:255 - (R0+ry))/511 (align_corners 2x).
        for (int e = tid; e < 703; e += 512) {
            const int y   = e / 19;
            const int xp  = e - 19 * y;
            const int x   = 2 * xp;
            const int ry  = y >> 1;
            const float wy =
                (float)((((y & 1) ? 510 : 255)) - (R0 + ry)) * (1.0f / 511.0f);
            const int Ax = C0 + xp;
            const float wx0 = (float)(255 - Ax) * (1.0f / 511.0f);
            const float wx1 = (float)(510 - Ax) * (1.0f / 511.0f);
            const bool oky = ((unsigned)(u0 + y) < 512u);
            const bool ok0 = oky && ((unsigned)(v0 + x) < 512u);
            const bool ok1 = oky && ((unsigned)(v0 + x + 1) < 512u) && (xp < 18);

            const char* lo = img_bytes + (ry * 21 + xp) * 16;
            const char* hi = lo + IMG_PLANE_B;
            const f32x4_t a00 = *(const f32x4_t*)(lo);
            const f32x4_t a01 = *(const f32x4_t*)(lo + 16);
            const f32x4_t a10 = *(const f32x4_t*)(lo + IMG_ROW_B);
            const f32x4_t a11 = *(const f32x4_t*)(lo + IMG_ROW_B + 16);
            const f32x4_t b00 = *(const f32x4_t*)(hi);
            const f32x4_t b01 = *(const f32x4_t*)(hi + 16);
            const f32x4_t b10 = *(const f32x4_t*)(hi + IMG_ROW_B);
            const f32x4_t b11 = *(const f32x4_t*)(hi + IMG_ROW_B + 16);

            const f32x4_t cA0 = a00 + wy * (a10 - a00);
            const f32x4_t cA1 = a01 + wy * (a11 - a01);
            const f32x4_t cB0 = b00 + wy * (b10 - b00);
            const f32x4_t cB1 = b01 + wy * (b11 - b01);

            // even output -> even buffer (linear store)
            {
                const f32x4_t va = cA0 + wx0 * (cA1 - cA0);
                const f32x4_t vb = cB0 + wx0 * (cB1 - cB0);
                __hip_bfloat162 h0 = __float22bfloat162_rn(make_float2(va[0], va[1]));
                __hip_bfloat162 h1 = __float22bfloat162_rn(make_float2(va[2], va[3]));
                __hip_bfloat162 h2 = __float22bfloat162_rn(make_float2(vb[0], vb[1]));
                __hip_bfloat162 h3 = __float22bfloat162_rn(make_float2(vb[2], vb[3]));
                union { short8_t s8; uint4 u4; } pk;
                pk.u4.x = ok0 ? *(unsigned int*)&h0 : 0u;
                pk.u4.y = ok0 ? *(unsigned int*)&h1 : 0u;
                pk.u4.z = ok0 ? *(unsigned int*)&h2 : 0u;
                pk.u4.w = ok0 ? *(unsigned int*)&h3 : 0u;
                *(short8_t*)(xup_bytes + y * XP_ROW + xp * 16) = pk.s8;
            }
            // odd output -> odd buffer; xp==18 writes the zero pad entry
            {
                const f32x4_t va = cA0 + wx1 * (cA1 - cA0);
                const f32x4_t vb = cB0 + wx1 * (cB1 - cB0);
                __hip_bfloat162 h0 = __float22bfloat162_rn(make_float2(va[0], va[1]));
                __hip_bfloat162 h1 = __float22bfloat162_rn(make_float2(va[2], va[3]));
                __hip_bfloat162 h2 = __float22bfloat162_rn(make_float2(vb[0], vb[1]));
                __hip_bfloat162 h3 = __float22bfloat162_rn(make_float2(vb[2], vb[3]));
                union { short8_t s8; uint4 u4; } pk;
                pk.u4.x = ok1 ? *(unsigned int*)&h0 : 0u;
                pk.u4.y = ok1 ? *(unsigned int*)&h1 : 0u;
                pk.u4.z = ok1 ? *(unsigned int*)&h2 : 0u;
                pk.u4.w = ok1 ? *(unsigned int*)&h3 : 0u;
                *(short8_t*)(xup_bytes + XO_BASE + y * XP_ROW + xp * 16) = pk.s8;
            }
        }
        __syncthreads();

        // ---- stage 3: 21 within-row pairs + 4 column pairs = 25 MFMAs ----
        const ushort* kbp = kerB + ((size_t)(oc * NPAIR_) * 64 + lane) * 8;
        // group A base: parity buffer = gs, row yb0+ky, entry tj+c
        const int baseA = (gs ? XO_BASE : 0) + yb0 * XP_ROW + tj * 16;
        // group B base: even buffer, row yb0+2q+gs, entry tj+3
        const int baseB = (yb0 + gs) * XP_ROW + (tj + 3) * 16;

        #pragma unroll
        for (int ky = 0; ky < KW_; ++ky) {
            short8_t bf0 = *(const short8_t*)(kbp + (size_t)((ky * 3 + 0) * 512));
            short8_t bf1 = *(const short8_t*)(kbp + (size_t)((ky * 3 + 1) * 512));
            short8_t bf2 = *(const short8_t*)(kbp + (size_t)((ky * 3 + 2) * 512));
            const int rbase = baseA + ky * XP_ROW;
            const short8_t a0 = *(const short8_t*)(xup_bytes + rbase);
            acc = __builtin_amdgcn_mfma_f32_32x32x16_bf16(a0, bf0, acc, 0, 0, 0);
            const short8_t a1 = *(const short8_t*)(xup_bytes + rbase + 16);
            acc = __builtin_amdgcn_mfma_f32_32x32x16_bf16(a1, bf1, acc, 0, 0, 0);
            const short8_t a2 = *(const short8_t*)(xup_bytes + rbase + 32);
            acc = __builtin_amdgcn_mfma_f32_32x32x16_bf16(a2, bf2, acc, 0, 0, 0);
        }
        #pragma unroll
        for (int q = 0; q < 4; ++q) {
            const short8_t bfq =
                *(const short8_t*)(kbp + (size_t)((21 + q) * 512));
            const short8_t aq =
                *(const short8_t*)(xup_bytes + baseB + q * (2 * XP_ROW));
            acc = __builtin_amdgcn_mfma_f32_32x32x16_bf16(aq, bfq, acc, 0, 0, 0);
        }
        __syncthreads();   // before next pass's staging overwrites LDS
    }

    // ---- epilogue: C-writes (layout col n=lane&31, row m=(q&3)+8*(q>>2)+4*gs)
    const int n = lane & 31;
    float* op = out + (size_t)(b * COUT_ + n) * (H_ * W_);
    const int ibase = i0 + 2 * w;
    #pragma unroll
    for (int grp = 0; grp < 4; ++grp) {
        const int ti  = ibase + (grp >> 1);
        const int tjj = j0 + ((grp & 1) ? 8 : 0) + 4 * gs;
        f32x4_t s;
        s[0] = acc[grp * 4 + 0]; s[1] = acc[grp * 4 + 1];
        s[2] = acc[grp * 4 + 2]; s[3] = acc[grp * 4 + 3];
        *(f32x4_t*)(op + (size_t)ti * W_ + tjj) = s;
    }

    // ---- epilogue: InstanceNorm partial sums from registers ----
    float s1 = 0.f, s2 = 0.f;
    #pragma unroll
    for (int q = 0; q < 16; ++q) { s1 += acc[q]; s2 = fmaf(acc[q], acc[q], s2); }
    s1 += __shfl_xor(s1, 32);
    s2 += __shfl_xor(s2, 32);
    if (lane < 32) { wp[w][lane][0] = s1; wp[w][lane][1] = s2; }
    __syncthreads();
    if (tid < 32) {
        float t1 = 0.f, t2 = 0.f;
        #pragma unroll
        for (int wv = 0; wv < 8; ++wv) { t1 += wp[wv][tid][0]; t2 += wp[wv][tid][1]; }
        const int tile = blockIdx.y * 16 + blockIdx.x;
        float2* pp = (float2*)partials;
        pp[((b * 32 + tid) << 8) | tile] = make_float2(t1, t2);
    }
}

// ============================================================
// Kernel C1: per-channel stats finalize. grid = 256 (one wave each).
// Fixed-order shfl tree -> deterministic.
// ============================================================
__global__ __launch_bounds__(64)
void stats_kernel(const float* __restrict__ partials, float* __restrict__ meanrs) {
    const int bo = blockIdx.x;                 // channel (b*32+o)
    const int l  = threadIdx.x;                // 0..63
    const float2* pp = (const float2*)partials + ((size_t)bo << 8);
    float s1 = 0.f, s2 = 0.f;
    #pragma unroll
    for (int k = 0; k < 4; ++k) {
        const float2 p = pp[l + 64 * k];
        s1 += p.x; s2 += p.y;
    }
    #pragma unroll
    for (int off = 32; off > 0; off >>= 1) {
        s1 += __shfl_down(s1, off);
        s2 += __shfl_down(s2, off);
    }
    if (l == 0) {
        const float inv = 1.0f / 65536.0f;
        const float m   = s1 * inv;
        const float var = s2 * inv - m * m;
        ((float2*)meanrs)[bo] = make_float2(m, 1.0f / sqrtf(var + EPS_));
    }
}

// ============================================================
// Kernel C2: pure-stream normalize + LeakyReLU (no LDS, no barriers).
// grid = 16384, block = 256.
// ============================================================
__global__ __launch_bounds__(256)
void norm2_kernel(float* __restrict__ y, const float* __restrict__ meanrs) {
    const int blk = blockIdx.x;
    const int bo  = blk >> 6;                  // 64 blocks per channel
    const float2 mr = ((const float2*)meanrs)[bo];
    const float m  = mr.x;
    const float rs = mr.y;

    const int e = blk * 256 + threadIdx.x;     // float4 index
    float4 v = ((const float4*)y)[e];
    v.x = (v.x - m) * rs; v.x = v.x >= 0.f ? v.x : SLOPE_ * v.x;
    v.y = (v.y - m) * rs; v.y = v.y >= 0.f ? v.y : SLOPE_ * v.y;
    v.z = (v.z - m) * rs; v.z = v.z >= 0.f ? v.z : SLOPE_ * v.z;
    v.w = (v.w - m) * rs; v.w = v.w >= 0.f ? v.w : SLOPE_ * v.w;
    ((float4*)y)[e] = v;
}

// ============================================================
extern "C" void kernel_launch(void* const* d_in, const int* in_sizes, int n_in,
                              void* d_out, int out_size, void* d_ws, size_t ws_size,
                              hipStream_t stream) {
    const float* image  = (const float*)d_in[0];
    const float* weight = (const float*)d_in[1];
    float*  out      = (float*)d_out;
    ushort* kerB     = (ushort*)d_ws;
    float*  partials = (float*)d_ws + PART_OFF_F;
    float*  meanrs   = (float*)d_ws + MEANRS_OFF_F;

    build_kernel<<<dim3(4 * NPAIR_), dim3(256), 0, stream>>>(weight, kerB);
    conv_mfma<<<dim3(16, 16, B_), dim3(512), 0, stream>>>(image, kerB, out, partials);
    stats_kernel<<<dim3(256), dim3(64), 0, stream>>>(partials, meanrs);
    norm2_kernel<<<dim3(16384), dim3(256), 0, stream>>>(out, meanrs);
}